// Round 3
// baseline (1062.295 us; speedup 1.0000x reference)
//
#include <hip/hip_runtime.h>

#define ROWS 2048
#define FLAT 33280
#define CHUNK_K 16640
#define S_DIM 520
#define C_IN 8
#define C_MID 64
#define SPLITK 8
#define SUBK 4160
#define BK 32
#define OUT_THETA 40960
#define OUT_MU 303104

// ---------------- K1: fused conv1+conv2 (half the o-channels) -> Ac (fp32) ----------------
__global__ __launch_bounds__(256) void k_conv(const float* __restrict__ x,
                                              const float* __restrict__ w1, const float* __restrict__ b1,
                                              const float* __restrict__ w2, const float* __restrict__ b2,
                                              float* __restrict__ Ac, int z) {
    __shared__ __align__(16) float xs[C_IN * S_DIM];     // 4160
    __shared__ float w1s[C_MID * C_IN];                  // 512
    __shared__ float b1s[C_MID];
    __shared__ __align__(16) float w2Ts[C_MID * 68];     // [c][o], pad 68
    __shared__ float b2s[C_MID];
    __shared__ __align__(16) float h1s[C_MID * 68];      // [c][s_local], pad 68

    int t = threadIdx.x;
    int bl = blockIdx.x;
    const float* xb = x + (size_t)bl * (C_IN * S_DIM);
    for (int i = t; i < C_IN * S_DIM; i += 256) xs[i] = xb[i];
    for (int i = t; i < C_MID * C_IN; i += 256) w1s[i] = w1[i];
    for (int i = t; i < C_MID * C_MID; i += 256) {
        int o = i >> 6, c = i & 63;
        w2Ts[c * 68 + o] = w2[i];
    }
    if (t < C_MID) { b1s[t] = b1[t]; b2s[t] = b2[t]; }
    __syncthreads();

    // conv2 thread tile: 4 o-channels x 2 s positions (32 o x 64 s per s-tile)
    int o0 = (t >> 5) * 4;          // 0,4,...,28 (local within 32-channel chunk)
    int sl0 = (t & 31) * 2;         // 0..62
    int obase = z * 32;             // global o offset of this chunk

    for (int tile = 0; tile < 9; ++tile) {
        int s0 = tile * 64;
        // h1 chunk: [64 c][64 s]
        for (int idx = t; idx < C_MID * 64; idx += 256) {
            int c = idx >> 6, ss = idx & 63;
            int s = s0 + ss;
            float acc = 0.f;
            if (s < S_DIM) {
                acc = b1s[c];
#pragma unroll
                for (int ci = 0; ci < C_IN; ++ci)
                    acc += w1s[c * C_IN + ci] * xs[ci * S_DIM + s];
                acc = fmaxf(acc, 0.f);
            }
            h1s[c * 68 + ss] = acc;
        }
        __syncthreads();

        // conv2: 4x2 register tile over the 32 chunk channels
        float acc[4][2];
#pragma unroll
        for (int i = 0; i < 4; i++) {
            acc[i][0] = b2s[obase + o0 + i];
            acc[i][1] = acc[i][0];
        }

        for (int c = 0; c < C_MID; c++) {
            float4 a = *reinterpret_cast<const float4*>(&w2Ts[c * 68 + obase + o0]);
            float2 h = *reinterpret_cast<const float2*>(&h1s[c * 68 + sl0]);
            float av[4] = { a.x, a.y, a.z, a.w };
#pragma unroll
            for (int i = 0; i < 4; i++) {
                acc[i][0] += av[i] * h.x;
                acc[i][1] += av[i] * h.y;
            }
        }

        int s = s0 + sl0;
        if (s < S_DIM) {
#pragma unroll
            for (int i = 0; i < 4; i++) {
                float2 st;
                st.x = fmaxf(acc[i][0], 0.f);
                st.y = fmaxf(acc[i][1], 0.f);
                *reinterpret_cast<float2*>(&Ac[(size_t)bl * CHUNK_K + (o0 + i) * S_DIM + s]) = st;
            }
        }
        __syncthreads();
    }
}

// ---------------- K2: pl1 GEMM chunk, split-K, fp32 ----------------
__global__ __launch_bounds__(256) void k_gemm(const float* __restrict__ Ac,
                                              const float* __restrict__ Bw,
                                              float* __restrict__ P, int z) {
    __shared__ __align__(16) float As[BK * 68];  // [k][row], stride 68
    __shared__ __align__(16) float Bs[BK * 68];  // [k][col]

    int t = threadIdx.x;
    int rt = blockIdx.x, ct = blockIdx.y, bz = blockIdx.z;
    int row0 = rt * 64, col0 = ct * 64;
    int klocal = bz * SUBK;                      // within chunk
    int kglobal = z * CHUNK_K + klocal;          // within FLAT

    int lr = t & 63;          // row/col within tile for staging
    int lk = (t >> 6) * 8;    // k offset (0,8,16,24)
    const float* Ap = Ac + (size_t)(row0 + lr) * CHUNK_K + klocal + lk;
    const float* Bp = Bw + (size_t)(col0 + lr) * FLAT + kglobal + lk;

    int tx = t & 15, ty = t >> 4;
    int m0 = ty * 4, n0 = tx * 4;
    float acc[4][4];
#pragma unroll
    for (int i = 0; i < 4; i++)
#pragma unroll
        for (int j = 0; j < 4; j++) acc[i][j] = 0.f;

    for (int it = 0; it < SUBK / BK; ++it) {
        float4 a0 = *reinterpret_cast<const float4*>(Ap);
        float4 a1 = *reinterpret_cast<const float4*>(Ap + 4);
        float4 b0 = *reinterpret_cast<const float4*>(Bp);
        float4 b1 = *reinterpret_cast<const float4*>(Bp + 4);
        __syncthreads();
        {
            float av[8] = { a0.x, a0.y, a0.z, a0.w, a1.x, a1.y, a1.z, a1.w };
            float bv[8] = { b0.x, b0.y, b0.z, b0.w, b1.x, b1.y, b1.z, b1.w };
#pragma unroll
            for (int j = 0; j < 8; j++) {
                As[(lk + j) * 68 + lr] = av[j];
                Bs[(lk + j) * 68 + lr] = bv[j];
            }
        }
        __syncthreads();
#pragma unroll
        for (int k = 0; k < BK; k++) {
            float4 a = *reinterpret_cast<const float4*>(&As[k * 68 + m0]);
            float4 b = *reinterpret_cast<const float4*>(&Bs[k * 68 + n0]);
            float av[4] = { a.x, a.y, a.z, a.w };
            float bv[4] = { b.x, b.y, b.z, b.w };
#pragma unroll
            for (int i = 0; i < 4; i++)
#pragma unroll
                for (int j = 0; j < 4; j++) acc[i][j] += av[i] * bv[j];
        }
        Ap += BK; Bp += BK;
    }

    // P slot: z*4 + bz  (8 slots total)
    float* Pp = P + (size_t)(z * 4 + bz) * (ROWS * 256);
#pragma unroll
    for (int i = 0; i < 4; i++) {
        float4 o4 = make_float4(acc[i][0], acc[i][1], acc[i][2], acc[i][3]);
        *reinterpret_cast<float4*>(&Pp[(size_t)(row0 + m0 + i) * 256 + col0 + n0]) = o4;
    }
}

// ---------------- K3: reduce + bias + relu + pl2 + Theta ----------------
__global__ __launch_bounds__(128) void k_head(const float* __restrict__ P,
                                              const float* __restrict__ pl1b,
                                              const float* __restrict__ pl2w,
                                              const float* __restrict__ pl2b,
                                              float* __restrict__ out) {
    __shared__ __align__(16) float hs[256];
    __shared__ float Rls[128];
    int row = blockIdx.x;
    int t = threadIdx.x;
    for (int c = t; c < 256; c += 128) {
        float v = pl1b[c];
#pragma unroll
        for (int z = 0; z < SPLITK; z++) v += P[(size_t)z * (ROWS * 256) + (size_t)row * 256 + c];
        hs[c] = fmaxf(v, 0.f);
    }
    __syncthreads();
    {
        float v = pl2b[t];
        const float4* wr = reinterpret_cast<const float4*>(pl2w + (size_t)t * 256);
        const float4* hv = reinterpret_cast<const float4*>(hs);
#pragma unroll 8
        for (int c4 = 0; c4 < 64; c4++) {
            float4 w = wr[c4], h = hv[c4];
            v += w.x * h.x + w.y * h.y + w.z * h.z + w.w * h.w;
        }
        Rls[t] = v;
    }
    __syncthreads();
    if (t < 64) {
        float pr = Rls[t], pi = Rls[64 + t];
        float nrm = fmaxf(sqrtf(pr * pr + pi * pi), 1e-12f);
        float* th = out + OUT_THETA + (size_t)row * 128 + t * 2;
        th[0] = pr / nrm;
        th[1] = pi / nrm;
    }
}

// ---------------- K4: einsums + MLPs + softmax + norm ----------------
__global__ __launch_bounds__(256) void k_tail(const float* __restrict__ Hre, const float* __restrict__ Him,
                                              const float* __restrict__ chre, const float* __restrict__ chim,
                                              const float* __restrict__ b1w, const float* __restrict__ b1b,
                                              const float* __restrict__ b2w, const float* __restrict__ b2b,
                                              const float* __restrict__ b3w, const float* __restrict__ b3b,
                                              const float* __restrict__ p1w, const float* __restrict__ p1b,
                                              const float* __restrict__ p2w, const float* __restrict__ p2b,
                                              float* __restrict__ out) {
    int b = blockIdx.x, t = threadIdx.x;
    __shared__ float trs[256], tis[256];         // [l][n]
    __shared__ float red[512];                   // [part][km][2]
    __shared__ __align__(16) float cH[64];
    __shared__ __align__(16) float u1[128];
    __shared__ __align__(16) float u2[128];
    __shared__ __align__(16) float q1[128];
    __shared__ float wv[80];
    __shared__ float sc[4];

    const float* th = out + OUT_THETA + (size_t)b * 512;
    for (int i = t; i < 256; i += 256) { trs[i] = th[2 * i]; tis[i] = th[2 * i + 1]; }
    __syncthreads();

    {
        int part = t >> 5, km = t & 31, k = km >> 3, m = km & 7;
        const float* hr = Hre + (size_t)b * 8192 + m * 1024 + k;
        const float* hi = Him + (size_t)b * 8192 + m * 1024 + k;
        float a1 = 0.f, a2 = 0.f;
        for (int n = part * 8; n < part * 8 + 8; n++) {
#pragma unroll
            for (int l = 0; l < 4; l++) {
                float re = hr[n * 16 + l * 4], im = hi[n * 16 + l * 4];
                float tr = trs[l * 64 + n], ti = tis[l * 64 + n];
                a1 += re * tr + im * ti;
                a2 += re * ti - im * tr;
            }
        }
        red[(part * 32 + km) * 2 + 0] = a1;
        red[(part * 32 + km) * 2 + 1] = a2;
    }
    __syncthreads();
    if (t < 32) {
        float top = 0.f, bot = 0.f;
#pragma unroll
        for (int p = 0; p < 8; p++) { top += red[(p * 32 + t) * 2]; bot += red[(p * 32 + t) * 2 + 1]; }
        int k2 = t >> 3, m2 = t & 7;
        cH[k2 * 16 + m2]     = top + chre[b * 32 + t];
        cH[k2 * 16 + 8 + m2] = bot + chim[b * 32 + t];
    }
    __syncthreads();

    const float4* ch4 = reinterpret_cast<const float4*>(cH);
    if (t < 128) {
        float v = b1b[t];
        const float4* w = reinterpret_cast<const float4*>(b1w + (size_t)t * 64);
#pragma unroll
        for (int j = 0; j < 16; j++) {
            float4 a = w[j], c = ch4[j];
            v += a.x * c.x + a.y * c.y + a.z * c.z + a.w * c.w;
        }
        u1[t] = fmaxf(v, 0.f);
    } else {
        int o = t - 128;
        float v = p1b[o];
        const float4* w = reinterpret_cast<const float4*>(p1w + (size_t)o * 64);
#pragma unroll
        for (int j = 0; j < 16; j++) {
            float4 a = w[j], c = ch4[j];
            v += a.x * c.x + a.y * c.y + a.z * c.z + a.w * c.w;
        }
        q1[o] = fmaxf(v, 0.f);
    }
    __syncthreads();

    if (t < 128) {
        float v = b2b[t];
        const float4* w = reinterpret_cast<const float4*>(b2w + (size_t)t * 128);
        const float4* uu = reinterpret_cast<const float4*>(u1);
#pragma unroll
        for (int j = 0; j < 32; j++) {
            float4 a = w[j], c = uu[j];
            v += a.x * c.x + a.y * c.y + a.z * c.z + a.w * c.w;
        }
        u2[t] = fmaxf(v, 0.f);
    } else if (t < 130) {
        int o = t - 128;
        float v = p2b[o];
        const float4* w = reinterpret_cast<const float4*>(p2w + (size_t)o * 128);
        const float4* qq = reinterpret_cast<const float4*>(q1);
#pragma unroll
        for (int j = 0; j < 32; j++) {
            float4 a = w[j], c = qq[j];
            v += a.x * c.x + a.y * c.y + a.z * c.z + a.w * c.w;
        }
        sc[o] = v;
    }
    __syncthreads();

    if (t < 80) {
        float v = b3b[t];
        const float4* w = reinterpret_cast<const float4*>(b3w + (size_t)t * 128);
        const float4* uu = reinterpret_cast<const float4*>(u2);
#pragma unroll
        for (int j = 0; j < 32; j++) {
            float4 a = w[j], c = uu[j];
            v += a.x * c.x + a.y * c.y + a.z * c.z + a.w * c.w;
        }
        wv[t] = v;
    }
    __syncthreads();

    if (t == 0) {
        float mx = fmaxf(sc[0], sc[1]);
        float e0 = expf(sc[0] - mx), e1 = expf(sc[1] - mx);
        float s = e0 + e1;
        float mu0 = e0 / s, mu1 = e1 / s;
        out[OUT_MU + b * 2]     = mu0;
        out[OUT_MU + b * 2 + 1] = mu1;
        float ss = 0.f;
        for (int j = 0; j < 80; j++) ss += wv[j] * wv[j];
        float wn = fmaxf(sqrtf(ss), 1e-12f);
        sc[2] = 3.16227766017f * sqrtf(mu0) / wn;
    }
    __syncthreads();
    if (t < 80) out[b * 80 + t] = wv[t] * sc[2];
}

extern "C" void kernel_launch(void* const* d_in, const int* in_sizes, int n_in,
                              void* d_out, int out_size, void* d_ws, size_t ws_size,
                              hipStream_t stream) {
    const float* x    = (const float*)d_in[0];
    const float* Hre  = (const float*)d_in[1];
    const float* Him  = (const float*)d_in[2];
    const float* chre = (const float*)d_in[3];
    const float* chim = (const float*)d_in[4];
    const float* c1w  = (const float*)d_in[5];
    const float* c1b  = (const float*)d_in[6];
    const float* c2w  = (const float*)d_in[7];
    const float* c2b  = (const float*)d_in[8];
    const float* pl1w = (const float*)d_in[9];
    const float* pl1b = (const float*)d_in[10];
    const float* pl2w = (const float*)d_in[11];
    const float* pl2b = (const float*)d_in[12];
    const float* b1w  = (const float*)d_in[13];
    const float* b1b  = (const float*)d_in[14];
    const float* b2w  = (const float*)d_in[15];
    const float* b2b  = (const float*)d_in[16];
    const float* b3w  = (const float*)d_in[17];
    const float* b3b  = (const float*)d_in[18];
    const float* p1w  = (const float*)d_in[19];
    const float* p1b  = (const float*)d_in[20];
    const float* p2w  = (const float*)d_in[21];
    const float* p2b  = (const float*)d_in[22];
    float* out = (float*)d_out;

    char* ws = (char*)d_ws;
    float* Ac = (float*)(ws + 0);              // 2048*16640 fp32 = 136,314,880 B
    float* P  = (float*)(ws + 136314880u);     // 8*2048*256 fp32 =  16,777,216 B (total 153 MB)

    // chunk 0: o-channels [0,32)
    k_conv<<<2048, 256, 0, stream>>>(x, c1w, c1b, c2w, c2b, Ac, 0);
    k_gemm<<<dim3(32, 4, 4), 256, 0, stream>>>(Ac, pl1w, P, 0);
    // chunk 1: o-channels [32,64)
    k_conv<<<2048, 256, 0, stream>>>(x, c1w, c1b, c2w, c2b, Ac, 1);
    k_gemm<<<dim3(32, 4, 4), 256, 0, stream>>>(Ac, pl1w, P, 1);

    k_head<<<2048, 128, 0, stream>>>(P, pl1b, pl2w, pl2b, out);
    k_tail<<<512, 256, 0, stream>>>(Hre, Him, chre, chim, b1w, b1b, b2w, b2b,
                                    b3w, b3b, p1w, p1b, p2w, p2b, out);
}

// Round 4
// 663.539 us; speedup vs baseline: 1.6010x; 1.6010x over previous
//
#include <hip/hip_runtime.h>

#define ROWS 2048
#define FLATK 33280
#define CHUNK_K 16640
#define SUBK 2080          // per split-k block: 65 * 32
#define NSTEP 65
#define S_DIM 520
#define SPLITP 16
#define OUT_THETA 40960
#define OUT_MU 303104
#define LOSCALE 2048.0f
#define INV_LOSCALE (1.0f/2048.0f)

typedef __attribute__((ext_vector_type(8))) _Float16 f16x8;
typedef __attribute__((ext_vector_type(4))) float f32x4;

union H16 { _Float16 h; unsigned short u; };

static __device__ __forceinline__ void split16(float v, unsigned short& hi, unsigned short& lo) {
    H16 a, b;
    a.h = (_Float16)v;
    float r = (v - (float)a.h) * LOSCALE;
    b.h = (_Float16)r;
    hi = a.u; lo = b.u;
}

// ---------------- K1: fused conv1+conv2 -> A hi/lo f16 planes ----------------
// grid (2048 bl, 9 s-tiles), 256 thr. Chunk z covers o in [32z, 32z+32).
__global__ __launch_bounds__(256) void k_conv(const float* __restrict__ x,
                                              const float* __restrict__ w1, const float* __restrict__ b1,
                                              const float* __restrict__ w2, const float* __restrict__ b2,
                                              unsigned short* __restrict__ Ah, unsigned short* __restrict__ Al,
                                              int z) {
    __shared__ __align__(16) float xs[8 * 64];       // [c][ss]
    __shared__ float w1s[512];
    __shared__ float b1s[64];
    __shared__ float b2s[32];
    __shared__ __align__(16) float w2s[64 * 36];     // [c][o_local], stride 36
    __shared__ __align__(16) float h1s[64 * 68];     // [c][ss], stride 68

    int t = threadIdx.x;
    int bl = blockIdx.x, st = blockIdx.y;
    int s0 = st * 64;
    int obase = z * 32;

    const float* xb = x + (size_t)bl * (8 * S_DIM);
    for (int i = t; i < 512; i += 256) {
        int c = i >> 6, ss = i & 63;
        int s = s0 + ss;
        xs[i] = (s < S_DIM) ? xb[c * S_DIM + s] : 0.f;
        w1s[i] = w1[i];
    }
    for (int i = t; i < 2048; i += 256) {
        int c = i >> 5, ol = i & 31;
        w2s[c * 36 + ol] = w2[(obase + ol) * 64 + c];
    }
    if (t < 64) b1s[t] = b1[t];
    if (t < 32) b2s[t] = b2[obase + t];
    __syncthreads();

    for (int i = t; i < 4096; i += 256) {
        int c = i >> 6, ss = i & 63;
        float acc = b1s[c];
#pragma unroll
        for (int ci = 0; ci < 8; ci++) acc += w1s[c * 8 + ci] * xs[ci * 64 + ss];
        h1s[c * 68 + ss] = fmaxf(acc, 0.f);
    }
    __syncthreads();

    int o0 = (t >> 5) * 4;       // 0..28 local
    int sl0 = (t & 31) * 2;      // 0..62
    float acc[4][2];
#pragma unroll
    for (int i = 0; i < 4; i++) { acc[i][0] = b2s[o0 + i]; acc[i][1] = acc[i][0]; }

    for (int c = 0; c < 64; c++) {
        float4 wv = *reinterpret_cast<const float4*>(&w2s[c * 36 + o0]);
        float2 hv = *reinterpret_cast<const float2*>(&h1s[c * 68 + sl0]);
        float av[4] = { wv.x, wv.y, wv.z, wv.w };
#pragma unroll
        for (int i = 0; i < 4; i++) {
            acc[i][0] += av[i] * hv.x;
            acc[i][1] += av[i] * hv.y;
        }
    }

    int s = s0 + sl0;
    if (s < S_DIM) {
#pragma unroll
        for (int i = 0; i < 4; i++) {
            float v0 = fmaxf(acc[i][0], 0.f);
            float v1 = fmaxf(acc[i][1], 0.f);
            unsigned short h0, l0, h1_, l1_;
            split16(v0, h0, l0);
            split16(v1, h1_, l1_);
            size_t off = (size_t)bl * CHUNK_K + (size_t)(o0 + i) * S_DIM + s;
            *reinterpret_cast<ushort2*>(&Ah[off]) = make_ushort2(h0, h1_);
            *reinterpret_cast<ushort2*>(&Al[off]) = make_ushort2(l0, l1_);
        }
    }
}

// ---------------- K2: MFMA GEMM, fp16 hi/lo 3-pass, fp32 acc ----------------
// tile 64 rows x 128 cols, BK=32, grid (32 rt, 2 ct, 8 sk)
__global__ __launch_bounds__(256, 1) void k_gemm(const unsigned short* __restrict__ Ah,
                                                 const unsigned short* __restrict__ Al,
                                                 const float* __restrict__ Bw,
                                                 float* __restrict__ P, int z) {
    __shared__ __align__(16) unsigned short As_h[64 * 40];
    __shared__ __align__(16) unsigned short As_l[64 * 40];
    __shared__ __align__(16) unsigned short Bs_h[128 * 40];
    __shared__ __align__(16) unsigned short Bs_l[128 * 40];

    int t = threadIdx.x;
    int rt = blockIdx.x, ct = blockIdx.y, sk = blockIdx.z;
    int row0 = rt * 64, col0 = ct * 128;
    int kb0 = sk * SUBK;

    // A staging: 64 rows x 4 chunks of 8 ushorts
    int sa_row = t >> 2, sa_kq = t & 3;
    const unsigned short* ApH = Ah + (size_t)(row0 + sa_row) * CHUNK_K + kb0 + sa_kq * 8;
    const unsigned short* ApL = Al + (size_t)(row0 + sa_row) * CHUNK_K + kb0 + sa_kq * 8;
    // B staging: 128 cols x 8 chunks of float4
    const float* Bp[4];
    int sb_col[4], sb_kq[4];
#pragma unroll
    for (int j = 0; j < 4; j++) {
        int c = t + 256 * j;
        sb_col[j] = c >> 3; sb_kq[j] = c & 7;
        Bp[j] = Bw + (size_t)(col0 + sb_col[j]) * FLATK + (size_t)z * CHUNK_K + kb0 + sb_kq[j] * 4;
    }

    uint4 ra_h = *reinterpret_cast<const uint4*>(ApH);
    uint4 ra_l = *reinterpret_cast<const uint4*>(ApL);
    float4 rb[4];
#pragma unroll
    for (int j = 0; j < 4; j++) rb[j] = *reinterpret_cast<const float4*>(Bp[j]);

    int w = t >> 6, lane = t & 63;
    int m = lane & 15, kg = lane >> 4;

    f32x4 acc_h[4][2], acc_m[4][2];
#pragma unroll
    for (int i = 0; i < 4; i++)
#pragma unroll
        for (int j = 0; j < 2; j++) {
            acc_h[i][j] = (f32x4){0.f, 0.f, 0.f, 0.f};
            acc_m[i][j] = (f32x4){0.f, 0.f, 0.f, 0.f};
        }

    for (int it = 0; it < NSTEP; ++it) {
        __syncthreads();
        *reinterpret_cast<uint4*>(&As_h[sa_row * 40 + sa_kq * 8]) = ra_h;
        *reinterpret_cast<uint4*>(&As_l[sa_row * 40 + sa_kq * 8]) = ra_l;
#pragma unroll
        for (int j = 0; j < 4; j++) {
            float4 v = rb[j];
            unsigned short h0, h1, h2, h3, l0, l1, l2, l3;
            split16(v.x, h0, l0); split16(v.y, h1, l1);
            split16(v.z, h2, l2); split16(v.w, h3, l3);
            *reinterpret_cast<ushort4*>(&Bs_h[sb_col[j] * 40 + sb_kq[j] * 4]) = make_ushort4(h0, h1, h2, h3);
            *reinterpret_cast<ushort4*>(&Bs_l[sb_col[j] * 40 + sb_kq[j] * 4]) = make_ushort4(l0, l1, l2, l3);
        }
        __syncthreads();

        if (it + 1 < NSTEP) {
            ApH += 32; ApL += 32;
            ra_h = *reinterpret_cast<const uint4*>(ApH);
            ra_l = *reinterpret_cast<const uint4*>(ApL);
#pragma unroll
            for (int j = 0; j < 4; j++) {
                Bp[j] += 32;
                rb[j] = *reinterpret_cast<const float4*>(Bp[j]);
            }
        }

        f16x8 a_h[4], a_l[4], b_h[2], b_l[2];
#pragma unroll
        for (int i = 0; i < 4; i++) {
            int off = (i * 16 + m) * 40 + kg * 8;
            a_h[i] = *reinterpret_cast<const f16x8*>(&As_h[off]);
            a_l[i] = *reinterpret_cast<const f16x8*>(&As_l[off]);
        }
#pragma unroll
        for (int j = 0; j < 2; j++) {
            int off = (w * 32 + j * 16 + m) * 40 + kg * 8;
            b_h[j] = *reinterpret_cast<const f16x8*>(&Bs_h[off]);
            b_l[j] = *reinterpret_cast<const f16x8*>(&Bs_l[off]);
        }
#pragma unroll
        for (int i = 0; i < 4; i++)
#pragma unroll
            for (int j = 0; j < 2; j++) {
                acc_h[i][j] = __builtin_amdgcn_mfma_f32_16x16x32_f16(a_h[i], b_h[j], acc_h[i][j], 0, 0, 0);
                acc_m[i][j] = __builtin_amdgcn_mfma_f32_16x16x32_f16(a_l[i], b_h[j], acc_m[i][j], 0, 0, 0);
                acc_m[i][j] = __builtin_amdgcn_mfma_f32_16x16x32_f16(a_h[i], b_l[j], acc_m[i][j], 0, 0, 0);
            }
    }

    // epilogue: C/D layout col=lane&15, row=(lane>>4)*4+reg
    float* Pp = P + (size_t)(z * 8 + sk) * (ROWS * 256);
    int rbase = row0 + (lane >> 4) * 4;
    int cbase = col0 + w * 32 + (lane & 15);
#pragma unroll
    for (int i = 0; i < 4; i++)
#pragma unroll
        for (int j = 0; j < 2; j++)
#pragma unroll
            for (int r = 0; r < 4; r++) {
                int rr = rbase + i * 16 + r;
                int cc = cbase + j * 16;
                Pp[(size_t)rr * 256 + cc] = acc_h[i][j][r] + acc_m[i][j][r] * INV_LOSCALE;
            }
}

// ---------------- K3: reduce + bias + relu + pl2 + Theta ----------------
__global__ __launch_bounds__(128) void k_head(const float* __restrict__ P,
                                              const float* __restrict__ pl1b,
                                              const float* __restrict__ pl2w,
                                              const float* __restrict__ pl2b,
                                              float* __restrict__ out) {
    __shared__ __align__(16) float hs[256];
    __shared__ float Rls[128];
    int row = blockIdx.x;
    int t = threadIdx.x;
    for (int c = t; c < 256; c += 128) {
        float v = pl1b[c];
#pragma unroll
        for (int zz = 0; zz < SPLITP; zz++) v += P[(size_t)zz * (ROWS * 256) + (size_t)row * 256 + c];
        hs[c] = fmaxf(v, 0.f);
    }
    __syncthreads();
    {
        float v = pl2b[t];
        const float4* wr = reinterpret_cast<const float4*>(pl2w + (size_t)t * 256);
        const float4* hv = reinterpret_cast<const float4*>(hs);
#pragma unroll 8
        for (int c4 = 0; c4 < 64; c4++) {
            float4 wq = wr[c4], h = hv[c4];
            v += wq.x * h.x + wq.y * h.y + wq.z * h.z + wq.w * h.w;
        }
        Rls[t] = v;
    }
    __syncthreads();
    if (t < 64) {
        float pr = Rls[t], pi = Rls[64 + t];
        float nrm = fmaxf(sqrtf(pr * pr + pi * pi), 1e-12f);
        float* th = out + OUT_THETA + (size_t)row * 128 + t * 2;
        th[0] = pr / nrm;
        th[1] = pi / nrm;
    }
}

// ---------------- K4: einsums + MLPs + softmax + norm ----------------
__global__ __launch_bounds__(256) void k_tail(const float* __restrict__ Hre, const float* __restrict__ Him,
                                              const float* __restrict__ chre, const float* __restrict__ chim,
                                              const float* __restrict__ b1w, const float* __restrict__ b1b,
                                              const float* __restrict__ b2w, const float* __restrict__ b2b,
                                              const float* __restrict__ b3w, const float* __restrict__ b3b,
                                              const float* __restrict__ p1w, const float* __restrict__ p1b,
                                              const float* __restrict__ p2w, const float* __restrict__ p2b,
                                              float* __restrict__ out) {
    int b = blockIdx.x, t = threadIdx.x;
    __shared__ float trs[256], tis[256];
    __shared__ float red[512];
    __shared__ __align__(16) float cH[64];
    __shared__ __align__(16) float u1[128];
    __shared__ __align__(16) float u2[128];
    __shared__ __align__(16) float q1[128];
    __shared__ float wv[80];
    __shared__ float sc[4];

    const float* th = out + OUT_THETA + (size_t)b * 512;
    for (int i = t; i < 256; i += 256) { trs[i] = th[2 * i]; tis[i] = th[2 * i + 1]; }
    __syncthreads();

    {
        int part = t >> 5, km = t & 31, k = km >> 3, m = km & 7;
        const float* hr = Hre + (size_t)b * 8192 + m * 1024 + k;
        const float* hi = Him + (size_t)b * 8192 + m * 1024 + k;
        float a1 = 0.f, a2 = 0.f;
        for (int n = part * 8; n < part * 8 + 8; n++) {
#pragma unroll
            for (int l = 0; l < 4; l++) {
                float re = hr[n * 16 + l * 4], im = hi[n * 16 + l * 4];
                float tr = trs[l * 64 + n], ti = tis[l * 64 + n];
                a1 += re * tr + im * ti;
                a2 += re * ti - im * tr;
            }
        }
        red[(part * 32 + km) * 2 + 0] = a1;
        red[(part * 32 + km) * 2 + 1] = a2;
    }
    __syncthreads();
    if (t < 32) {
        float top = 0.f, bot = 0.f;
#pragma unroll
        for (int p = 0; p < 8; p++) { top += red[(p * 32 + t) * 2]; bot += red[(p * 32 + t) * 2 + 1]; }
        int k2 = t >> 3, m2 = t & 7;
        cH[k2 * 16 + m2]     = top + chre[b * 32 + t];
        cH[k2 * 16 + 8 + m2] = bot + chim[b * 32 + t];
    }
    __syncthreads();

    const float4* ch4 = reinterpret_cast<const float4*>(cH);
    if (t < 128) {
        float v = b1b[t];
        const float4* wq = reinterpret_cast<const float4*>(b1w + (size_t)t * 64);
#pragma unroll
        for (int j = 0; j < 16; j++) {
            float4 a = wq[j], c = ch4[j];
            v += a.x * c.x + a.y * c.y + a.z * c.z + a.w * c.w;
        }
        u1[t] = fmaxf(v, 0.f);
    } else {
        int o = t - 128;
        float v = p1b[o];
        const float4* wq = reinterpret_cast<const float4*>(p1w + (size_t)o * 64);
#pragma unroll
        for (int j = 0; j < 16; j++) {
            float4 a = wq[j], c = ch4[j];
            v += a.x * c.x + a.y * c.y + a.z * c.z + a.w * c.w;
        }
        q1[o] = fmaxf(v, 0.f);
    }
    __syncthreads();

    if (t < 128) {
        float v = b2b[t];
        const float4* wq = reinterpret_cast<const float4*>(b2w + (size_t)t * 128);
        const float4* uu = reinterpret_cast<const float4*>(u1);
#pragma unroll
        for (int j = 0; j < 32; j++) {
            float4 a = wq[j], c = uu[j];
            v += a.x * c.x + a.y * c.y + a.z * c.z + a.w * c.w;
        }
        u2[t] = fmaxf(v, 0.f);
    } else if (t < 130) {
        int o = t - 128;
        float v = p2b[o];
        const float4* wq = reinterpret_cast<const float4*>(p2w + (size_t)o * 128);
        const float4* qq = reinterpret_cast<const float4*>(q1);
#pragma unroll
        for (int j = 0; j < 32; j++) {
            float4 a = wq[j], c = qq[j];
            v += a.x * c.x + a.y * c.y + a.z * c.z + a.w * c.w;
        }
        sc[o] = v;
    }
    __syncthreads();

    if (t < 80) {
        float v = b3b[t];
        const float4* wq = reinterpret_cast<const float4*>(b3w + (size_t)t * 128);
        const float4* uu = reinterpret_cast<const float4*>(u2);
#pragma unroll
        for (int j = 0; j < 32; j++) {
            float4 a = wq[j], c = uu[j];
            v += a.x * c.x + a.y * c.y + a.z * c.z + a.w * c.w;
        }
        wv[t] = v;
    }
    __syncthreads();

    if (t == 0) {
        float mx = fmaxf(sc[0], sc[1]);
        float e0 = expf(sc[0] - mx), e1 = expf(sc[1] - mx);
        float s = e0 + e1;
        float mu0 = e0 / s, mu1 = e1 / s;
        out[OUT_MU + b * 2]     = mu0;
        out[OUT_MU + b * 2 + 1] = mu1;
        float ss = 0.f;
        for (int j = 0; j < 80; j++) ss += wv[j] * wv[j];
        float wn = fmaxf(sqrtf(ss), 1e-12f);
        sc[2] = 3.16227766017f * sqrtf(mu0) / wn;
    }
    __syncthreads();
    if (t < 80) out[b * 80 + t] = wv[t] * sc[2];
}

extern "C" void kernel_launch(void* const* d_in, const int* in_sizes, int n_in,
                              void* d_out, int out_size, void* d_ws, size_t ws_size,
                              hipStream_t stream) {
    const float* x    = (const float*)d_in[0];
    const float* Hre  = (const float*)d_in[1];
    const float* Him  = (const float*)d_in[2];
    const float* chre = (const float*)d_in[3];
    const float* chim = (const float*)d_in[4];
    const float* c1w  = (const float*)d_in[5];
    const float* c1b  = (const float*)d_in[6];
    const float* c2w  = (const float*)d_in[7];
    const float* c2b  = (const float*)d_in[8];
    const float* pl1w = (const float*)d_in[9];
    const float* pl1b = (const float*)d_in[10];
    const float* pl2w = (const float*)d_in[11];
    const float* pl2b = (const float*)d_in[12];
    const float* b1w  = (const float*)d_in[13];
    const float* b1b  = (const float*)d_in[14];
    const float* b2w  = (const float*)d_in[15];
    const float* b2b  = (const float*)d_in[16];
    const float* b3w  = (const float*)d_in[17];
    const float* b3b  = (const float*)d_in[18];
    const float* p1w  = (const float*)d_in[19];
    const float* p1b  = (const float*)d_in[20];
    const float* p2w  = (const float*)d_in[21];
    const float* p2b  = (const float*)d_in[22];
    float* out = (float*)d_out;

    char* ws = (char*)d_ws;
    unsigned short* Ah = (unsigned short*)(ws + 0);           // 2048*16640 f16 = 68,157,440 B
    unsigned short* Al = (unsigned short*)(ws + 68157440u);   // 68,157,440 B
    float* P           = (float*)(ws + 136314880u);           // 16*2048*256 fp32 = 33,554,432 B
                                                              // total 169,869,312 B (<= proven 170 MB)

    for (int z = 0; z < 2; z++) {
        k_conv<<<dim3(2048, 9), 256, 0, stream>>>(x, c1w, c1b, c2w, c2b, Ah, Al, z);
        k_gemm<<<dim3(32, 2, 8), 256, 0, stream>>>(Ah, Al, pl1w, P, z);
    }
    k_head<<<2048, 128, 0, stream>>>(P, pl1b, pl2w, pl2b, out);
    k_tail<<<512, 256, 0, stream>>>(Hre, Him, chre, chim, b1w, b1b, b2w, b2b,
                                    b3w, b3b, p1w, p1b, p2w, p2b, out);
}